// Round 8
// baseline (11772.925 us; speedup 1.0000x reference)
//
#include <hip/hip_runtime.h>
#include <stdint.h>

#define HDIM  512
#define NCLS  1000

// ---------------- workspace (bytes) ----------------
// ring : h[layer][slot=t&3][batch 64][unit 512] f32 = 6 MB
// bar  : 2 groups x 128 arrival slots + flags
#define RING_F   (3 * 4 * 64 * 512)
#define BAR_OFF  ((size_t)RING_F * 4)
#define WS_NEED  (BAR_OFF + 4096)

typedef _Float16 f16x8 __attribute__((ext_vector_type(8)));
typedef float    f32x4 __attribute__((ext_vector_type(4)));

// B-operand LDS: 224 k-octets (x:32, h0/h1/h2:64 each) x 16 batches, hi/lo f16
#define OB_X   0
#define OB_H0  32
#define OB_H1  96
#define OB_H2  160
#define NOCT   224
#define OSTR   136          // 16 batches x 8 f16 + 8 pad (2-way banks max)

__device__ __forceinline__ float sigf(float x) {
    return 1.f / (1.f + __expf(-x));
}
__device__ __forceinline__ float tanh_fast(float x) {
    x = fminf(fmaxf(x, -15.f), 15.f);
    const float e = __expf(2.f * x);
    return (e - 1.f) / (e + 1.f);
}
struct f16pair { _Float16 h, l; };
__device__ __forceinline__ f16pair cvt2(float x) {
    f16pair p;
    p.h = (_Float16)x;
    p.l = (_Float16)(x - (float)p.h);
    return p;
}
__device__ __forceinline__ void cvt_store8(float4 A0, float4 A1,
                                           _Float16* dh, _Float16* dl) {
    f16x8 hi, lo; f16pair p;
    p = cvt2(A0.x); hi[0] = p.h; lo[0] = p.l;
    p = cvt2(A0.y); hi[1] = p.h; lo[1] = p.l;
    p = cvt2(A0.z); hi[2] = p.h; lo[2] = p.l;
    p = cvt2(A0.w); hi[3] = p.h; lo[3] = p.l;
    p = cvt2(A1.x); hi[4] = p.h; lo[4] = p.l;
    p = cvt2(A1.y); hi[5] = p.h; lo[5] = p.l;
    p = cvt2(A1.z); hi[6] = p.h; lo[6] = p.l;
    p = cvt2(A1.w); hi[7] = p.h; lo[7] = p.l;
    *(f16x8*)dh = hi; *(f16x8*)dl = lo;
}

// =====================================================================
// Persistent pipelined 3-layer LSTM.  grid = 256 WGs x 256 thr, 1 WG/CU.
// WG: g = bid&1 (32 batches), s = bid>>1 (units 4s..4s+3, all 4 gates,
// all 3 layers).  Wave = layer: wv0 L0 ([x;h0] K=768), wv1 L1 ([h0;h1]
// K=1024), wv2 L2 ([h1;h2] K=1024); weight rows live in registers as
// f16 hi/lo MFMA A-frags.  Cycle n: L0 t=n, L1 t=n-1, L2 t=n-2.
// Per cycle: 2 passes of 16 batches (shared hi/lo B-LDS buffer):
// conv -> sync -> MFMA (input+hidden fused, 3-term f16x2 split) -> sync
// -> pointwise (c in registers) -> ring store.  Then group barrier
// (store-arrive, master-wave poll, flag release, acquire fence).
// =====================================================================
__global__ __launch_bounds__(256, 1) void lstm_mega(
        const float* __restrict__ x,      // [64][512][256]
        const float* __restrict__ Wih0, const float* __restrict__ Whh0,
        const float* __restrict__ bih0, const float* __restrict__ bhh0,
        const float* __restrict__ Wih1, const float* __restrict__ Whh1,
        const float* __restrict__ bih1, const float* __restrict__ bhh1,
        const float* __restrict__ Wih2, const float* __restrict__ Whh2,
        const float* __restrict__ bih2, const float* __restrict__ bhh2,
        float* __restrict__ ring,         // [3][4][64][512]
        uint32_t* __restrict__ bar)       // arr[g][128] = bar[g*128+s]; flag[g] = bar[256+g*16]
{
    __shared__ _Float16 hb_hi[NOCT * OSTR];   // 60928 B
    __shared__ _Float16 hb_lo[NOCT * OSTR];   // 60928 B
    __shared__ float gates_t[3 * 16 * 17];    // [layer][row][batch16]

    const int tid  = threadIdx.x;
    const int bid  = blockIdx.x;
    const int g    = bid & 1;
    const int s    = bid >> 1;            // 0..127
    uint32_t* arr  = bar + g * 128;
    uint32_t* flg  = bar + 256 + g * 16;

    const int wv   = tid >> 6;
    const int lane = tid & 63;
    const int m16  = lane & 15;           // A-row (gate*4+du) / B-col (batch)
    const int quad = lane >> 4;

    // ---- A-fragments: weight rows in registers, f16 hi/lo, once at start
    // row r = m16: gate = r>>2, du = r&3 -> global gate-row = gate*512 + 4s + du
    f16x8 a_hi[32], a_lo[32];
    {
        const int grow = (m16 >> 2) * 512 + (s << 2) + (m16 & 3);
        const float* srcA; const float* srcB; int segN, nkt;
        if (wv == 0)      { srcA = Wih0 + (size_t)grow * 256; srcB = Whh0 + (size_t)grow * 512; segN = 8;  nkt = 24; }
        else if (wv == 1) { srcA = Wih1 + (size_t)grow * 512; srcB = Whh1 + (size_t)grow * 512; segN = 16; nkt = 32; }
        else if (wv == 2) { srcA = Wih2 + (size_t)grow * 512; srcB = Whh2 + (size_t)grow * 512; segN = 16; nkt = 32; }
        else              { srcA = Wih0; srcB = Whh0; segN = 8; nkt = 0; }
        #pragma unroll
        for (int kt = 0; kt < 32; kt++) {
            if (kt < nkt) {
                const float* sp = (kt < segN) ? srcA + kt * 32 + (quad << 3)
                                              : srcB + (kt - segN) * 32 + (quad << 3);
                const float4 w0 = *(const float4*)sp;
                const float4 w1 = *(const float4*)(sp + 4);
                f16pair p;
                p = cvt2(w0.x); a_hi[kt][0] = p.h; a_lo[kt][0] = p.l;
                p = cvt2(w0.y); a_hi[kt][1] = p.h; a_lo[kt][1] = p.l;
                p = cvt2(w0.z); a_hi[kt][2] = p.h; a_lo[kt][2] = p.l;
                p = cvt2(w0.w); a_hi[kt][3] = p.h; a_lo[kt][3] = p.l;
                p = cvt2(w1.x); a_hi[kt][4] = p.h; a_lo[kt][4] = p.l;
                p = cvt2(w1.y); a_hi[kt][5] = p.h; a_lo[kt][5] = p.l;
                p = cvt2(w1.z); a_hi[kt][6] = p.h; a_lo[kt][6] = p.l;
                p = cvt2(w1.w); a_hi[kt][7] = p.h; a_lo[kt][7] = p.l;
            }
        }
    }
    // wave-uniform MFMA constants
    const int nkt   = (wv == 0) ? 24 : ((wv < 3) ? 32 : 0);
    const int segN  = (wv == 0) ? 8 : 16;
    const int baseA = (wv == 0) ? OB_X  : ((wv == 1) ? OB_H0 : OB_H1);
    const int baseB = (wv == 0) ? OB_H0 : ((wv == 1) ? OB_H1 : OB_H2);

    // ---- biases (pointwise lanes: du = lane&3, b16 = lane>>2)
    const int du = lane & 3, b16 = lane >> 2;
    float bias_i = 0.f, bias_f = 0.f, bias_g = 0.f, bias_o = 0.f;
    if (wv < 3) {
        const float* bi = (wv == 0) ? bih0 : ((wv == 1) ? bih1 : bih2);
        const float* bh = (wv == 0) ? bhh0 : ((wv == 1) ? bhh1 : bhh2);
        const int u = (s << 2) + du;
        bias_i = bi[u]        + bh[u];
        bias_f = bi[512 + u]  + bh[512 + u];
        bias_g = bi[1024 + u] + bh[1024 + u];
        bias_o = bi[1536 + u] + bh[1536 + u];
    }
    float c_reg[2] = {0.f, 0.f};

    // conversion mapping: cb = batch-in-pass, ck = octet selector
    const int cb = tid >> 4, ck = tid & 15;

    for (int n = 0; n < 514; n++) {
        const int  tl     = n - wv;                       // this wave's timestep
        const bool active = (wv < 3) && (tl >= 0) && (tl < 512);

        #pragma unroll
        for (int p = 0; p < 2; p++) {
            const int batch = (g << 5) + (p << 4) + cb;

            // ---- conversion: 4 vectors -> hi/lo f16 B-LDS (all 256 threads)
            {   // V0 = x[batch][n][:]  (zeros when n >= 512)
                const bool v = (n < 512);
                const float* src = x + ((size_t)batch * 512 + n) * 256;
                #pragma unroll
                for (int it = 0; it < 2; it++) {
                    const int oct = ck + (it << 4);
                    float4 A0 = {0.f,0.f,0.f,0.f}, A1 = {0.f,0.f,0.f,0.f};
                    if (v) { A0 = *(const float4*)&src[oct << 3];
                             A1 = *(const float4*)&src[(oct << 3) + 4]; }
                    cvt_store8(A0, A1, &hb_hi[(OB_X + oct) * OSTR + (cb << 3)],
                                        &hb_lo[(OB_X + oct) * OSTR + (cb << 3)]);
                }
            }
            #pragma unroll
            for (int vec = 1; vec <= 3; vec++) {          // V1=h0[n-1],V2=h1[n-2],V3=h2[n-3]
                const int  tsrc = n - vec;
                const bool v    = (tsrc >= 0) && (tsrc < 512);
                const float* src = ring + ((((size_t)(vec - 1) * 4 + (tsrc & 3)) * 64 + batch) << 9);
                const int obase  = 32 + (vec - 1) * 64;
                #pragma unroll
                for (int it = 0; it < 4; it++) {
                    const int oct = ck + (it << 4);
                    float4 A0 = {0.f,0.f,0.f,0.f}, A1 = {0.f,0.f,0.f,0.f};
                    if (v) { A0 = *(const float4*)&src[oct << 3];
                             A1 = *(const float4*)&src[(oct << 3) + 4]; }
                    cvt_store8(A0, A1, &hb_hi[(obase + oct) * OSTR + (cb << 3)],
                                        &hb_lo[(obase + oct) * OSTR + (cb << 3)]);
                }
            }
            __syncthreads();

            // ---- MFMA: fused input+hidden GEMV, 3-term f16x2 split
            if (active) {
                f32x4 acc = {0.f, 0.f, 0.f, 0.f};
                #pragma unroll
                for (int kt = 0; kt < 32; kt++) {
                    if (kt < nkt) {
                        const int ob = ((kt < segN) ? baseA + (kt << 2)
                                                    : baseB + ((kt - segN) << 2)) + quad;
                        const f16x8 bh8 = *(const f16x8*)&hb_hi[ob * OSTR + (m16 << 3)];
                        const f16x8 bl8 = *(const f16x8*)&hb_lo[ob * OSTR + (m16 << 3)];
                        acc = __builtin_amdgcn_mfma_f32_16x16x32_f16(a_hi[kt], bh8, acc, 0, 0, 0);
                        acc = __builtin_amdgcn_mfma_f32_16x16x32_f16(a_lo[kt], bh8, acc, 0, 0, 0);
                        acc = __builtin_amdgcn_mfma_f32_16x16x32_f16(a_hi[kt], bl8, acc, 0, 0, 0);
                    }
                }
                // C/D: col(batch)=m16, row=quad*4+reg
                #pragma unroll
                for (int j = 0; j < 4; j++)
                    gates_t[wv * 272 + ((quad << 2) + j) * 17 + m16] = acc[j];
            }
            __syncthreads();

            // ---- pointwise (waves 0-2, 64 lanes = 4 units x 16 batches)
            if (active) {
                const float vi = gates_t[wv * 272 + du * 17 + b16]        + bias_i;
                const float vf = gates_t[wv * 272 + (4 + du) * 17 + b16]  + bias_f;
                const float vg = gates_t[wv * 272 + (8 + du) * 17 + b16]  + bias_g;
                const float vo = gates_t[wv * 272 + (12 + du) * 17 + b16] + bias_o;
                const float gi = sigf(vi);
                const float gf = sigf(vf);
                const float gg = tanh_fast(vg);
                const float go = sigf(vo);
                const float c  = fmaf(gf, c_reg[p], gi * gg);
                c_reg[p] = c;
                const float h = go * tanh_fast(c);
                const int bpw = (g << 5) + (p << 4) + b16;
                float* hp = ring + ((((size_t)wv * 4 + (tl & 3)) * 64 + bpw) << 9)
                                 + (s << 2) + du;
                __hip_atomic_store(hp, h, __ATOMIC_RELAXED, __HIP_MEMORY_SCOPE_AGENT);
            }
        }

        // ---- group barrier (skip after last cycle)
        if (n < 513) {
            __syncthreads();              // drain vmcnt: ring stores at LLC
            const uint32_t tgt = (uint32_t)(n + 1);
            if (tid == 0)
                __hip_atomic_store(&arr[s], tgt, __ATOMIC_RELEASE,
                                   __HIP_MEMORY_SCOPE_AGENT);
            if (s == 0 && tid < 64) {     // master WG: wave 0 watches 128 slots
                while (!__all((int)(
                        __hip_atomic_load(&arr[lane], __ATOMIC_RELAXED,
                                          __HIP_MEMORY_SCOPE_AGENT) >= tgt &&
                        __hip_atomic_load(&arr[64 + lane], __ATOMIC_RELAXED,
                                          __HIP_MEMORY_SCOPE_AGENT) >= tgt)))
                    __builtin_amdgcn_s_sleep(1);
                if (tid == 0)
                    __hip_atomic_store(flg, tgt, __ATOMIC_RELEASE,
                                       __HIP_MEMORY_SCOPE_AGENT);
            }
            if (tid == 0) {
                while (__hip_atomic_load(flg, __ATOMIC_RELAXED,
                                         __HIP_MEMORY_SCOPE_AGENT) < tgt)
                    __builtin_amdgcn_s_sleep(1);
                __builtin_amdgcn_fence(__ATOMIC_ACQUIRE, "agent");
            }
            __syncthreads();
        }
    }
}

// =====================================================================
// FC head: out[b][c] = h2_final[b][:] . W_fc[c][:] + b_fc[c]
// =====================================================================
__global__ __launch_bounds__(256) void fc_head(
        const float* __restrict__ hl,      // [64][512] (ring slot of t=511)
        const float* __restrict__ Wfc,     // [1000][512]
        const float* __restrict__ bfc,
        float* __restrict__ out)           // [64][1000]
{
    __shared__ float hs[HDIM];
    const int b = blockIdx.x;
    const float* hb = hl + (size_t)b * HDIM;
    for (int i = threadIdx.x; i < HDIM; i += 256) hs[i] = hb[i];
    __syncthreads();
    const int wave = threadIdx.x >> 6, lane = threadIdx.x & 63;
    for (int c = wave; c < NCLS; c += 4) {
        const float* wr = Wfc + (size_t)c * HDIM;
        float s = 0.f;
        for (int k = lane; k < HDIM; k += 64) s = fmaf(hs[k], wr[k], s);
        #pragma unroll
        for (int off = 32; off > 0; off >>= 1) s += __shfl_down(s, off, 64);
        if (lane == 0) out[b * NCLS + c] = s + bfc[c];
    }
}

// =====================================================================
extern "C" void kernel_launch(void* const* d_in, const int* in_sizes, int n_in,
                              void* d_out, int out_size, void* d_ws, size_t ws_size,
                              hipStream_t stream)
{
    (void)in_sizes; (void)n_in; (void)out_size;
    if (ws_size < WS_NEED) return;   // readable failure instead of OOB fault

    const float* x    = (const float*)d_in[0];
    const float* Wih0 = (const float*)d_in[1];
    const float* Whh0 = (const float*)d_in[2];
    const float* bih0 = (const float*)d_in[3];
    const float* bhh0 = (const float*)d_in[4];
    const float* Wih1 = (const float*)d_in[5];
    const float* Whh1 = (const float*)d_in[6];
    const float* bih1 = (const float*)d_in[7];
    const float* bhh1 = (const float*)d_in[8];
    const float* Wih2 = (const float*)d_in[9];
    const float* Whh2 = (const float*)d_in[10];
    const float* bih2 = (const float*)d_in[11];
    const float* bhh2 = (const float*)d_in[12];
    const float* Wfc  = (const float*)d_in[13];
    const float* bfc  = (const float*)d_in[14];
    float* out = (float*)d_out;

    char* ws = (char*)d_ws;
    float* ring = (float*)ws;
    uint32_t* bar = (uint32_t*)(ws + BAR_OFF);

    (void)hipMemsetAsync(bar, 0, 4096, stream);

    lstm_mega<<<dim3(256), dim3(256), 0, stream>>>(
        x, Wih0, Whh0, bih0, bhh0, Wih1, Whh1, bih1, bhh1,
        Wih2, Whh2, bih2, bhh2, ring, bar);

    // h2[t=511] lives in ring[layer=2][slot=511&3=3]
    const float* h_last = ring + ((size_t)(2 * 4 + 3) * 64 * 512);
    fc_head<<<dim3(64), dim3(256), 0, stream>>>(h_last, Wfc, bfc, out);
}

// Round 9
// 6196.735 us; speedup vs baseline: 1.8999x; 1.8999x over previous
//
#include <hip/hip_runtime.h>
#include <stdint.h>

#define HDIM  512
#define NCLS  1000

typedef _Float16 f16x8 __attribute__((ext_vector_type(8)));
typedef float    f32x4 __attribute__((ext_vector_type(4)));

// ---------------- workspace (bytes) ----------------
// xcv hi/lo : [64][512][256] f16 = 16 MB each (pre-converted x)
// rh  hi/lo : [3][4][64][512] f16 = 1.5 MB each (h ring, depth 4)
// bar       : 4 groups x 64 arrival slots + flags
#define XCVH_OFF 0UL
#define XCVL_OFF 16777216UL
#define RHH_OFF  33554432UL
#define RHL_OFF  35127296UL
#define BAR_OFF  36700160UL
#define WS_NEED  (BAR_OFF + 4096UL)

// LDS B-operand layout: hb[batch 16][oct 0..223][8 f16], row = 225 octs*16B = 3600 B
// (900 dwords = 4 mod 32 -> MFMA b128 reads across batches are 2-way = free;
//  staging writes are lane-contiguous -> conflict-free)
#define OCT_TOT 224
#define H_ROW   1800              // f16 per batch row (3600 B)
#define HB_F16  (16 * H_ROW)      // 28800 f16 = 57600 B per plane

__device__ __forceinline__ float sigf(float x) {
    return 1.f / (1.f + __expf(-x));
}
__device__ __forceinline__ float tanh_fast(float x) {
    x = fminf(fmaxf(x, -15.f), 15.f);
    const float e = __expf(2.f * x);
    return (e - 1.f) / (e + 1.f);
}
struct f16pair { _Float16 h, l; };
__device__ __forceinline__ f16pair cvt2(float x) {
    f16pair p;
    p.h = (_Float16)x;
    p.l = (_Float16)(x - (float)p.h);
    return p;
}
__device__ __forceinline__ uint32_t pack2(_Float16 a, _Float16 b) {
    union { _Float16 f[2]; uint32_t u; } U;
    U.f[0] = a; U.f[1] = b;
    return U.u;
}

// =====================================================================
// Prologue: x (f32) -> hi/lo f16 planes, once per call.
// =====================================================================
__global__ __launch_bounds__(256) void xcvt(
        const float* __restrict__ x, _Float16* __restrict__ xh,
        _Float16* __restrict__ xl, int n)
{
    const int stride = gridDim.x * 256;
    for (int i = blockIdx.x * 256 + threadIdx.x; i < n; i += stride) {
        const f16pair p = cvt2(x[i]);
        xh[i] = p.h;
        xl[i] = p.l;
    }
}

// =====================================================================
// Persistent pipelined 3-layer LSTM.  grid = 256 WGs x 512 thr (8 waves),
// 1 WG/CU (121 KB LDS).  WG: g = bid&3 (16 batches), s = bid>>2 (8 units).
// Wave w<6: layer l = w>>1, gate-pair gtile = w&1; A-rows (16) = 2 gates x
// 8 units, full K in registers as f16 hi/lo frags.  Cycle n: L0 t=n,
// L1 t=n-1, L2 t=n-2.  Per cycle: stage x[n],h0[n-1],h1[n-2],h2[n-3]
// (pre-split f16 planes -> plain copies into [batch][oct] LDS) -> sync ->
// MFMA (fused input+hidden, 3-term split) -> sync -> pointwise (waves 0-2,
// 2 units/thread, c in regs, packed u32 h-stores to ring planes) ->
// group barrier (store-arrive, master-wave poll, flag, acquire fence).
// =====================================================================
__global__ __launch_bounds__(512, 1) void lstm_mega(
        const _Float16* __restrict__ xh, const _Float16* __restrict__ xl,
        const float* __restrict__ Wih0, const float* __restrict__ Whh0,
        const float* __restrict__ bih0, const float* __restrict__ bhh0,
        const float* __restrict__ Wih1, const float* __restrict__ Whh1,
        const float* __restrict__ bih1, const float* __restrict__ bhh1,
        const float* __restrict__ Wih2, const float* __restrict__ Whh2,
        const float* __restrict__ bih2, const float* __restrict__ bhh2,
        _Float16* __restrict__ rhh,      // [3][4][64][512] hi plane
        _Float16* __restrict__ rhl,      // lo plane
        uint32_t* __restrict__ bar)      // arr[g][64]=bar[g*64+s]; flag[g]=bar[256+g*16]
{
    __shared__ _Float16 hb_hi[HB_F16];      // 57600 B
    __shared__ _Float16 hb_lo[HB_F16];      // 57600 B
    __shared__ float gates_t[3 * 32 * 17];  // [layer][gate*8+du][batch16], 6528 B

    const int tid  = threadIdx.x;
    const int bid  = blockIdx.x;
    const int g    = bid & 3;             // batch group (16 batches)
    const int s    = bid >> 2;            // unit slice: units 8s..8s+7
    uint32_t* arr  = bar + g * 64;
    uint32_t* flg  = bar + 256 + g * 16;

    const int wv   = tid >> 6;            // 0..7
    const int lane = tid & 63;
    const int m16  = lane & 15;
    const int quad = lane >> 4;

    // ---- A-fragments (waves 0-5): weight rows in registers, f16 hi/lo
    f16x8 a_hi[32], a_lo[32];
    const int lw    = wv >> 1;            // frag layer
    const int gtile = wv & 1;             // gate pair {2gt,2gt+1}
    const int nkt   = (lw == 0) ? 24 : 32;
    const int segN  = (lw == 0) ? 8 : 16;
    if (wv < 6) {
        const int gate = (gtile << 1) + (m16 >> 3);
        const int grow = gate * 512 + (s << 3) + (m16 & 7);
        const float* Wih = (lw == 0) ? Wih0 : ((lw == 1) ? Wih1 : Wih2);
        const float* Whh = (lw == 0) ? Whh0 : ((lw == 1) ? Whh1 : Whh2);
        const int Kin = (lw == 0) ? 256 : 512;
        const float* srcA = Wih + (size_t)grow * Kin;
        const float* srcB = Whh + (size_t)grow * 512;
        #pragma unroll
        for (int kt = 0; kt < 32; kt++) {
            if (kt < nkt) {
                const float* sp = (kt < segN) ? srcA + kt * 32 + (quad << 3)
                                              : srcB + (kt - segN) * 32 + (quad << 3);
                const float4 w0 = *(const float4*)sp;
                const float4 w1 = *(const float4*)(sp + 4);
                f16pair p;
                p = cvt2(w0.x); a_hi[kt][0] = p.h; a_lo[kt][0] = p.l;
                p = cvt2(w0.y); a_hi[kt][1] = p.h; a_lo[kt][1] = p.l;
                p = cvt2(w0.z); a_hi[kt][2] = p.h; a_lo[kt][2] = p.l;
                p = cvt2(w0.w); a_hi[kt][3] = p.h; a_lo[kt][3] = p.l;
                p = cvt2(w1.x); a_hi[kt][4] = p.h; a_lo[kt][4] = p.l;
                p = cvt2(w1.y); a_hi[kt][5] = p.h; a_lo[kt][5] = p.l;
                p = cvt2(w1.z); a_hi[kt][6] = p.h; a_lo[kt][6] = p.l;
                p = cvt2(w1.w); a_hi[kt][7] = p.h; a_lo[kt][7] = p.l;
            }
        }
    }
    // B-layout oct base per frag layer: L0 reads octs 0..95 (x,h0),
    // L1 32..159 (h0,h1), L2 96..223 (h1,h2)
    const int lboct = (lw == 0) ? 0 : ((lw == 1) ? 32 : 96);

    // ---- pointwise mapping (tid<192): l = tid>>6, 2 units/thread
    const int pl  = tid >> 6;             // == wave index 0..2
    const int pr  = tid & 63;
    const int du2 = pr & 3;               // unit pair
    const int b16 = pr >> 2;              // batch in group
    float bias_v[4][2];
    if (tid < 192) {
        const float* bi = (pl == 0) ? bih0 : ((pl == 1) ? bih1 : bih2);
        const float* bh = (pl == 0) ? bhh0 : ((pl == 1) ? bhh1 : bhh2);
        #pragma unroll
        for (int gate = 0; gate < 4; gate++)
            #pragma unroll
            for (int j = 0; j < 2; j++) {
                const int u = (s << 3) + (du2 << 1) + j;
                bias_v[gate][j] = bi[gate * 512 + u] + bh[gate * 512 + u];
            }
    }
    float c_reg[2] = {0.f, 0.f};

    // ---- staging mapping: sb = batch, ol = chunk lane
    const int sb  = tid >> 5;             // 0..15
    const int ol  = tid & 31;             // 0..31
    const int b64 = (g << 4) + sb;

    for (int n = 0; n < 514; n++) {
        // ================= stage B operands (plain f16 copies) =================
        {   // i=0: x[n] octs 0..31
            f16x8 vh = {}, vl = {};
            if (n < 512) {
                const size_t off = (((size_t)b64 * 512 + n) << 8) + (ol << 3);
                vh = *(const f16x8*)(xh + off);
                vl = *(const f16x8*)(xl + off);
            }
            const int d = sb * H_ROW + (ol << 3);
            *(f16x8*)&hb_hi[d] = vh;
            *(f16x8*)&hb_lo[d] = vl;
        }
        #pragma unroll
        for (int i = 1; i < 7; i++) {     // h_l[n-1-l], octs 64 each
            const int l    = (i - 1) >> 1;
            const int octw = ol + (((i - 1) & 1) << 5);
            const int ts   = n - 1 - l;
            f16x8 vh = {}, vl = {};
            if (ts >= 0 && ts < 512) {
                const size_t off = ((((size_t)l << 2) + (ts & 3)) * 64 + b64) * 512
                                 + ((size_t)octw << 3);
                vh = *(const f16x8*)(rhh + off);
                vl = *(const f16x8*)(rhl + off);
            }
            const int d = sb * H_ROW + ((32 + (l << 6) + octw) << 3);
            *(f16x8*)&hb_hi[d] = vh;
            *(f16x8*)&hb_lo[d] = vl;
        }
        __syncthreads();

        // ================= MFMA (waves 0-5) =================
        const int tl = n - lw;
        if (wv < 6 && tl >= 0 && tl < 512) {
            f32x4 acc = {0.f, 0.f, 0.f, 0.f};
            #pragma unroll
            for (int kt = 0; kt < 32; kt++) {
                if (kt < nkt) {
                    const int d = m16 * H_ROW + ((lboct + (kt << 2) + quad) << 3);
                    const f16x8 bh8 = *(const f16x8*)&hb_hi[d];
                    const f16x8 bl8 = *(const f16x8*)&hb_lo[d];
                    acc = __builtin_amdgcn_mfma_f32_16x16x32_f16(a_hi[kt], bh8, acc, 0, 0, 0);
                    acc = __builtin_amdgcn_mfma_f32_16x16x32_f16(a_lo[kt], bh8, acc, 0, 0, 0);
                    acc = __builtin_amdgcn_mfma_f32_16x16x32_f16(a_hi[kt], bl8, acc, 0, 0, 0);
                }
            }
            // C/D: col(batch)=m16, row m = quad*4+j; within-layer row = gtile*16+m
            #pragma unroll
            for (int j = 0; j < 4; j++)
                gates_t[lw * 544 + ((gtile << 4) + (quad << 2) + j) * 17 + m16] = acc[j];
        }
        __syncthreads();

        // ================= pointwise (waves 0-2, 2 units/thread) =================
        const int tp = n - pl;
        if (tid < 192 && tp >= 0 && tp < 512) {
            _Float16 hh[2], hl2[2];
            #pragma unroll
            for (int j = 0; j < 2; j++) {
                const int du = (du2 << 1) + j;
                const float vi = gates_t[pl * 544 + (du) * 17 + b16]      + bias_v[0][j];
                const float vf = gates_t[pl * 544 + (8 + du) * 17 + b16]  + bias_v[1][j];
                const float vg = gates_t[pl * 544 + (16 + du) * 17 + b16] + bias_v[2][j];
                const float vo = gates_t[pl * 544 + (24 + du) * 17 + b16] + bias_v[3][j];
                const float gi = sigf(vi);
                const float gf = sigf(vf);
                const float gg = tanh_fast(vg);
                const float go = sigf(vo);
                const float c  = fmaf(gf, c_reg[j], gi * gg);
                c_reg[j] = c;
                const float h = go * tanh_fast(c);
                const f16pair p = cvt2(h);
                hh[j] = p.h; hl2[j] = p.l;
            }
            const size_t off = ((((size_t)pl << 2) + (tp & 3)) * 64 + (g << 4) + b16) * 512
                             + (s << 3) + (du2 << 1);
            __hip_atomic_store((uint32_t*)(rhh + off), pack2(hh[0], hh[1]),
                               __ATOMIC_RELAXED, __HIP_MEMORY_SCOPE_AGENT);
            __hip_atomic_store((uint32_t*)(rhl + off), pack2(hl2[0], hl2[1]),
                               __ATOMIC_RELAXED, __HIP_MEMORY_SCOPE_AGENT);
        }

        // ================= group barrier (64 WGs) =================
        if (n < 513) {
            __syncthreads();              // drain vmcnt: ring stores at LLC
            const uint32_t tgt = (uint32_t)(n + 1);
            if (tid == 0)
                __hip_atomic_store(&arr[s], tgt, __ATOMIC_RELEASE,
                                   __HIP_MEMORY_SCOPE_AGENT);
            if (s == 0 && tid < 64) {     // master WG: wave 0 watches 64 slots
                while (!__all((int)(__hip_atomic_load(&arr[lane], __ATOMIC_RELAXED,
                                                      __HIP_MEMORY_SCOPE_AGENT) >= tgt)))
                    __builtin_amdgcn_s_sleep(1);
                if (tid == 0)
                    __hip_atomic_store(flg, tgt, __ATOMIC_RELEASE,
                                       __HIP_MEMORY_SCOPE_AGENT);
            }
            if (tid == 0) {
                while (__hip_atomic_load(flg, __ATOMIC_RELAXED,
                                         __HIP_MEMORY_SCOPE_AGENT) < tgt)
                    __builtin_amdgcn_s_sleep(1);
                __builtin_amdgcn_fence(__ATOMIC_ACQUIRE, "agent");
            }
            __syncthreads();
        }
    }
}

// =====================================================================
// FC head: out[b][c] = (h2_hi+h2_lo)[b][:] . W_fc[c][:] + b_fc[c]
// =====================================================================
__global__ __launch_bounds__(256) void fc_head(
        const _Float16* __restrict__ rhh, const _Float16* __restrict__ rhl,
        const float* __restrict__ Wfc, const float* __restrict__ bfc,
        float* __restrict__ out)           // [64][1000]
{
    __shared__ float hs[HDIM];
    const int b = blockIdx.x;
    // h2[t=511]: layer 2, slot 511&3 = 3
    const size_t off = ((size_t)(2 * 4 + 3) * 64 + b) * 512;
    for (int i = threadIdx.x; i < HDIM; i += 256)
        hs[i] = (float)rhh[off + i] + (float)rhl[off + i];
    __syncthreads();
    const int wave = threadIdx.x >> 6, lane = threadIdx.x & 63;
    for (int c = wave; c < NCLS; c += 4) {
        const float* wr = Wfc + (size_t)c * HDIM;
        float s = 0.f;
        for (int k = lane; k < HDIM; k += 64) s = fmaf(hs[k], wr[k], s);
        #pragma unroll
        for (int off2 = 32; off2 > 0; off2 >>= 1) s += __shfl_down(s, off2, 64);
        if (lane == 0) out[b * NCLS + c] = s + bfc[c];
    }
}

// =====================================================================
extern "C" void kernel_launch(void* const* d_in, const int* in_sizes, int n_in,
                              void* d_out, int out_size, void* d_ws, size_t ws_size,
                              hipStream_t stream)
{
    (void)in_sizes; (void)n_in; (void)out_size;
    if (ws_size < WS_NEED) return;   // readable failure instead of OOB fault

    const float* x    = (const float*)d_in[0];
    const float* Wih0 = (const float*)d_in[1];
    const float* Whh0 = (const float*)d_in[2];
    const float* bih0 = (const float*)d_in[3];
    const float* bhh0 = (const float*)d_in[4];
    const float* Wih1 = (const float*)d_in[5];
    const float* Whh1 = (const float*)d_in[6];
    const float* bih1 = (const float*)d_in[7];
    const float* bhh1 = (const float*)d_in[8];
    const float* Wih2 = (const float*)d_in[9];
    const float* Whh2 = (const float*)d_in[10];
    const float* bih2 = (const float*)d_in[11];
    const float* bhh2 = (const float*)d_in[12];
    const float* Wfc  = (const float*)d_in[13];
    const float* bfc  = (const float*)d_in[14];
    float* out = (float*)d_out;

    char* ws = (char*)d_ws;
    _Float16* xh  = (_Float16*)(ws + XCVH_OFF);
    _Float16* xl  = (_Float16*)(ws + XCVL_OFF);
    _Float16* rhh = (_Float16*)(ws + RHH_OFF);
    _Float16* rhl = (_Float16*)(ws + RHL_OFF);
    uint32_t* bar = (uint32_t*)(ws + BAR_OFF);

    (void)hipMemsetAsync(bar, 0, 4096, stream);
    xcvt<<<dim3(2048), dim3(256), 0, stream>>>(x, xh, xl, 64 * 512 * 256);

    lstm_mega<<<dim3(256), dim3(512), 0, stream>>>(
        xh, xl, Wih0, Whh0, bih0, bhh0, Wih1, Whh1, bih1, bhh1,
        Wih2, Whh2, bih2, bhh2, rhh, rhl, bar);

    fc_head<<<dim3(64), dim3(256), 0, stream>>>(rhh, rhl, Wfc, bfc, out);
}